// Round 5
// baseline (6859.695 us; speedup 1.0000x reference)
//
#include <hip/hip_runtime.h>
#include <stdint.h>
#include <stddef.h>

// Persistent 2-layer LSTM decoder, B=1024, H=256, T=512.
//
// R9: antiphase co-residency with a register budget that actually fits.
// R5/R7: ~16-18k of ~23k cyc/step is barrier-skew/broadcast stall that
// intra-wave reordering cannot fill (R7 null: filling arrive->wait windows
// helps only non-critical WGs; the critical path is the LAST WG + discovery).
// Only another resident wave covers that => 2 blocks/CU from DIFFERENT
// groups (antiphase). R6 proved the 512-block/launch_bounds(256,2)/slot-claim
// skeleton runs; it spilled because 272 weight VGPRs >> 128. R8 hung -
// prime suspect: agent-scope (sc0 sc1) flag store vs sc0-only poll read
// (visibility level mismatch at the XCD L2). So R9:
//  - 16 groups x 32 WGs x 8 units/WG (512 blocks, 2/CU, 2 waves/SIMD).
//  - Gate-pair packing: ONE 16-row B-tile per wave ({i|g} or {f|o});
//    combine via __shfl_xor(.,8). Weight regs: bL0[10]+bL1h0[8] = 72 VGPR.
//  - Whh1 h1-half (16KB) + Wfc (32KB) in LDS, chunked f16 B-frags.
//  - c-state in LDS; pred and feedback x FUSED into one f16 LDS buffer
//    (in-place softmax). Live regs ~115 <= 128.
//  - Barrier: the R4-R7 PROVEN workgroup-scope RMW arrive/poll + buffer_inv
//    sc0 acquire (zz = opaque zero defeats the atomicrmw-add-0 fold).
//    Its RMW contention is exactly what the antiphase partner covers.
//  - h-buffers parity double-buffered (race-free without SB0 staging).
//
// h-buffer layout (per group, per layer, per parity): chunked f16
//   f16_index = (c*64 + m)*8 + e, c = unit/8 (0..31), m = chain (0..63),
//   e = unit%8. A-fragment (8 consecutive k for one m) = one 16B chunk.
//   Each WG owns chunk c == w.

#define NGROUP 16
#define GWG    32
#define NTHR   256
#define TSTEPS 512

typedef _Float16 half8 __attribute__((ext_vector_type(8)));
typedef float    f32x4 __attribute__((ext_vector_type(4)));

#define OUT_ELEMS   33554432   // 1024*512*64
#define HF_ELEMS    524288     // 2*1024*256
#define HBUF_ELEMS  16384      // 64*256 (f16) per layer per parity
#define GROUP_WS_BYTES 131072  // 2 layers * 2 parity * 32KB
#define WS_HBUF_OFF 4096
#define WS_NEEDED   (WS_HBUF_OFF + NGROUP * GROUP_WS_BYTES)

__device__ __forceinline__ float sigm(float x)   { return 1.0f / (1.0f + __expf(-x)); }
__device__ __forceinline__ float tanh_f(float x) { return 1.0f - 2.0f / (__expf(2.0f * x) + 1.0f); }

// XCD-local group barrier (R4-R7 proven mechanism, GWG=32). Entry
// __syncthreads drains vmcnt (write-through L1 => prior stores in XCD L2).
// Arrive/poll are real RMWs at the L2; acquire = L1-only invalidate.
__device__ __forceinline__ void group_barrier(int* ctr, int* phase, int zz) {
  __syncthreads();
  if (threadIdx.x == 0) {
    __hip_atomic_fetch_add(ctr, 1, __ATOMIC_RELEASE, __HIP_MEMORY_SCOPE_WORKGROUP);
    const int target = GWG * (++(*phase));
    while (__hip_atomic_fetch_add(ctr, zz, __ATOMIC_RELAXED, __HIP_MEMORY_SCOPE_WORKGROUP) < target)
      __builtin_amdgcn_s_sleep(1);
    asm volatile("buffer_inv sc0" ::: "memory");   // L1-only invalidate (gfx940+)
  }
  __syncthreads();
}

// 16B A-fragment plain load from a chunked h-buffer in L2.
__device__ __forceinline__ half8 ld_frag(const _Float16* buf, int idx16) {
  return *(const half8*)(buf + (size_t)idx16 * 8);
}

// Packed f16x2 store of (unit u, unit u+1) for chain m into own chunk c==w.
// Called on even u < 8 lanes only.
__device__ __forceinline__ void store_h_pair8(_Float16* hw, int w, int u, int m,
                                              float lo, float hi) {
  union { _Float16 h[2]; uint32_t u32; } pk;
  pk.h[0] = (_Float16)lo; pk.h[1] = (_Float16)hi;
  *((uint32_t*)hw + (size_t)(w * 64 + m) * 4 + (u >> 1)) = pk.u32;
}

__global__ __launch_bounds__(NTHR, 2)
void decoder_kernel(const float* __restrict__ h0in, const float* __restrict__ c0in,
                    const float* __restrict__ Wih0, const float* __restrict__ Whh0,
                    const float* __restrict__ bih0, const float* __restrict__ bhh0,
                    const float* __restrict__ Wih1, const float* __restrict__ Whh1,
                    const float* __restrict__ bih1, const float* __restrict__ bhh1,
                    const float* __restrict__ Wfc,  const float* __restrict__ bfc,
                    float* __restrict__ out, char* __restrict__ ws)
{
  const int tid  = threadIdx.x;
  const int lane = tid & 63;
  const int wave = tid >> 6;
  const int mi   = wave >> 1;   // M half (32 chains via mt loop)
  const int ni   = wave & 1;    // gate pair: 0 -> {i|g}, 1 -> {f|o}
  const int q    = lane >> 4;   // quad (k-chunk / chain group of 4)
  const int u    = lane & 15;   // B-tile row: u<8 unit u gateA, u>=8 unit u-8 gateB

  // Opaque zero: an SGPR the compiler cannot constant-fold.
  int zz;
  asm volatile("s_mov_b32 %0, 0" : "=s"(zz));

  // ---- derive (group g, member w) from the physical XCD id ----
  // 512 blocks => 64 slots/XCD => 2 groups/XCD (32 WGs each). Round-robin
  // dispatch puts slots {i, i+32} on one CU => different groups (antiphase).
  __shared__ int s_gw[2];
  if (tid == 0) {
    uint32_t xcc;
    asm volatile("s_getreg_b32 %0, hwreg(HW_REG_XCC_ID)" : "=s"(xcc));
    xcc &= 7;
    const int slot = atomicAdd((int*)(ws + 2048) + (size_t)xcc * 32, 1);  // device-scope, once
    s_gw[0] = (int)xcc * 2 + (slot >> 5);   // group 0..15
    s_gw[1] = slot & 31;                    // member 0..31 (8-unit slice)
  }
  __syncthreads();
  const int g = s_gw[0];
  const int w = s_gw[1];

  int* ctr = (int*)(ws + (size_t)g * 128);
  _Float16* hb_base = (_Float16*)(ws + WS_HBUF_OFF + (size_t)g * GROUP_WS_BYTES);
  auto hbL = [&](int layer, int par) { return hb_base + (size_t)(layer * 2 + par) * HBUF_ELEMS; };

  __shared__ __align__(16) _Float16 wfc[16384];     // Wfc chunked f16 (32KB)
  __shared__ __align__(16) _Float16 wl1h[8192];     // Whh1 rows of this WG, chunked (16KB)
  __shared__ __align__(16) _Float16 predx[64 * 72]; // pred (f16) -> in-place softmax -> x
  __shared__ __align__(16) float    exch[64 * 8];   // u0 per (chain, unit-in-WG)
  __shared__ __align__(16) float    cst[1024];      // c-state [layer][chain][unit]

  // ---------------- weight fragments ----------------
  // gates = act @ W^T. One packed B-tile per wave: rows {gateA u0..7, gateB u0..7}.
  // torch gate order: i(0), f(256), g(512), o(768).
  half8 bL0[10];   // L0: K = 64(x) + 256(h0)
  half8 bL1[8];    // L1 h0new-half: K-chunks 0..7 (Wih1)
  float biasL0, biasL1, biasFC[2];
  {
    const int gbase = (ni == 0) ? ((u < 8) ? 0 : 512) : ((u < 8) ? 256 : 768);
    const int grow  = gbase + w * 8 + (u & 7);
    biasL0 = bih0[grow] + bhh0[grow];
    biasL1 = bih1[grow] + bhh1[grow];
    #pragma unroll
    for (int kt = 0; kt < 10; ++kt) {
      const int k0 = kt * 32 + q * 8;
      const float* src = (kt < 2) ? (Wih0 + (size_t)grow * 64 + k0)
                                  : (Whh0 + (size_t)grow * 256 + (k0 - 64));
      half8 v;
      #pragma unroll
      for (int j = 0; j < 8; ++j) v[j] = (_Float16)src[j];
      bL0[kt] = v;
    }
    #pragma unroll
    for (int kt = 0; kt < 8; ++kt) {
      const float* src = Wih1 + (size_t)grow * 256 + kt * 32 + q * 8;
      half8 v;
      #pragma unroll
      for (int j = 0; j < 8; ++j) v[j] = (_Float16)src[j];
      bL1[kt] = v;
    }
    #pragma unroll
    for (int nt = 0; nt < 2; ++nt) biasFC[nt] = bfc[ni * 32 + nt * 16 + u];
  }
  // Wfc -> LDS chunked: frag (c, rowF) at (c*64 + rowF)*8, c = k/8.
  for (int i = tid; i < 2048; i += NTHR) {
    const int rowF = i & 63;
    const int c    = i >> 6;
    const float* s = Wfc + (size_t)rowF * 256 + c * 8;
    half8 v;
    #pragma unroll
    for (int j = 0; j < 8; ++j) v[j] = (_Float16)s[j];
    *(half8*)(wfc + (size_t)(c * 64 + rowF) * 8) = v;
  }
  // Whh1 (h1-half of L1, this WG's 32 rows = 4 gates x 8 units) -> LDS.
  // Row rho = ni'*16 + u' (same mapping the reading wave uses).
  for (int i = tid; i < 1024; i += NTHR) {
    const int rho = i & 31;
    const int c   = i >> 5;           // k/8 over h1's K=256
    const int n2  = rho >> 4;
    const int u2  = rho & 15;
    const int grow2 = ((n2 == 0) ? ((u2 < 8) ? 0 : 512) : ((u2 < 8) ? 256 : 768)) + w * 8 + (u2 & 7);
    const float* s = Whh1 + (size_t)grow2 * 256 + c * 8;
    half8 v;
    #pragma unroll
    for (int j = 0; j < 8; ++j) v[j] = (_Float16)s[j];
    *(half8*)(wl1h + (size_t)(c * 32 + rho) * 8) = v;
  }

  // ---------------- state init ----------------
  if (ni == 1 && u < 8) {   // c-state -> LDS, owned by ni=1 u<8 lanes
    #pragma unroll
    for (int mt = 0; mt < 2; ++mt)
      #pragma unroll
      for (int r = 0; r < 4; ++r) {
        const int m = mi * 32 + mt * 16 + q * 4 + r;
        cst[m * 8 + u]       = c0in[(size_t)(g * 64 + m) * 256 + w * 8 + u];
        cst[512 + m * 8 + u] = c0in[262144 + (size_t)(g * 64 + m) * 256 + w * 8 + u];
      }
  }
  // initial h -> parity-1 chunked buffers: each WG writes its own chunk c==w.
  if (tid < 128) {
    const int m  = tid >> 1;
    const int e0 = (tid & 1) * 4;
    #pragma unroll
    for (int l = 0; l < 2; ++l) {
      const float* s = h0in + (size_t)l * 262144 + (size_t)(g * 64 + m) * 256 + w * 8 + e0;
      union { _Float16 h[4]; uint64_t u64; } pk;
      #pragma unroll
      for (int j = 0; j < 4; ++j) pk.h[j] = (_Float16)s[j];
      *((uint64_t*)hbL(l, 1) + ((size_t)(w * 64 + m) * 2 + (e0 >> 2))) = pk.u64;
    }
  }
  for (int i = tid; i < 64 * 64; i += NTHR) {  // x0 = zeros, col 61 (= INPUT_SIZE-3) = 1
    const int row = i >> 6, col = i & 63;
    predx[row * 72 + col] = (col == 61) ? (_Float16)1.0f : (_Float16)0.0f;
  }

  int phase = 0;
  group_barrier(ctr, &phase, zz);

  // ---------------- time loop ----------------
  for (int t = 0; t < TSTEPS; ++t) {
    // ======== Layer 0: gates = [x | h0_prev] @ W^T ========
    {
      const _Float16* h0rd = hbL(0, (t + 1) & 1);
      f32x4 acc[2];
      #pragma unroll
      for (int mt = 0; mt < 2; ++mt) {
        f32x4 v; v[0] = biasL0; v[1] = biasL0; v[2] = biasL0; v[3] = biasL0;
        acc[mt] = v;
      }
      #pragma unroll
      for (int kt = 0; kt < 10; ++kt) {
        half8 a[2];
        #pragma unroll
        for (int mt = 0; mt < 2; ++mt) {
          const int m = mi * 32 + mt * 16 + u;
          if (kt < 2) a[mt] = *(const half8*)(predx + m * 72 + kt * 32 + q * 8);
          else        a[mt] = ld_frag(h0rd, (kt * 4 - 8 + q) * 64 + m);
        }
        #pragma unroll
        for (int mt = 0; mt < 2; ++mt)
          acc[mt] = __builtin_amdgcn_mfma_f32_16x16x32_f16(a[mt], bL0[kt], acc[mt], 0, 0, 0);
      }
      if (ni == 0) {  // lanes u<8: v=i, partner=g
        #pragma unroll
        for (int mt = 0; mt < 2; ++mt)
          #pragma unroll
          for (int r = 0; r < 4; ++r) {
            const float v  = acc[mt][r];
            const float pv = __shfl_xor(v, 8);
            const float u0 = sigm(v) * tanh_f(pv);
            if (u < 8)
              exch[(mi * 32 + mt * 16 + q * 4 + r) * 8 + u] = u0;
          }
      }
      __syncthreads();
      if (ni == 1) {  // lanes u<8: v=f, partner=o
        _Float16* h0wr = hbL(0, t & 1);
        #pragma unroll
        for (int mt = 0; mt < 2; ++mt)
          #pragma unroll
          for (int r = 0; r < 4; ++r) {
            const float v  = acc[mt][r];
            const float pv = __shfl_xor(v, 8);
            const int   m  = mi * 32 + mt * 16 + q * 4 + r;
            const float u0 = (u < 8) ? exch[m * 8 + u] : 0.0f;
            const float co = (u < 8) ? cst[m * 8 + u] : 0.0f;
            const float cn = sigm(v) * co + u0;
            const float hh = sigm(pv) * tanh_f(cn);
            if (u < 8) cst[m * 8 + u] = cn;
            const float other = __shfl_xor(hh, 1);
            if (!(u & 1) && u < 8)
              store_h_pair8(h0wr, w, u, m, hh, other);
          }
      }
    }
    group_barrier(ctr, &phase, zz);   // b1: h0(t) visible group-wide

    // ======== Layer 1: gates = [h0_new | h1_prev] @ W^T ========
    {
      const _Float16* h0nw = hbL(0, t & 1);
      const _Float16* h1rd = hbL(1, (t + 1) & 1);
      f32x4 acc[2];
      #pragma unroll
      for (int mt = 0; mt < 2; ++mt) {
        f32x4 v; v[0] = biasL1; v[1] = biasL1; v[2] = biasL1; v[3] = biasL1;
        acc[mt] = v;
      }
      #pragma unroll
      for (int kt = 0; kt < 8; ++kt) {   // h0new half, weights in regs
        half8 a[2];
        #pragma unroll
        for (int mt = 0; mt < 2; ++mt) {
          const int m = mi * 32 + mt * 16 + u;
          a[mt] = ld_frag(h0nw, (kt * 4 + q) * 64 + m);
        }
        #pragma unroll
        for (int mt = 0; mt < 2; ++mt)
          acc[mt] = __builtin_amdgcn_mfma_f32_16x16x32_f16(a[mt], bL1[kt], acc[mt], 0, 0, 0);
      }
      #pragma unroll
      for (int kt = 0; kt < 8; ++kt) {   // h1 half, weights from LDS
        const half8 b = *(const half8*)(wl1h + (size_t)((kt * 4 + q) * 32 + ni * 16 + u) * 8);
        half8 a[2];
        #pragma unroll
        for (int mt = 0; mt < 2; ++mt) {
          const int m = mi * 32 + mt * 16 + u;
          a[mt] = ld_frag(h1rd, (kt * 4 + q) * 64 + m);
        }
        #pragma unroll
        for (int mt = 0; mt < 2; ++mt)
          acc[mt] = __builtin_amdgcn_mfma_f32_16x16x32_f16(a[mt], b, acc[mt], 0, 0, 0);
      }
      if (ni == 0) {
        #pragma unroll
        for (int mt = 0; mt < 2; ++mt)
          #pragma unroll
          for (int r = 0; r < 4; ++r) {
            const float v  = acc[mt][r];
            const float pv = __shfl_xor(v, 8);
            const float u0 = sigm(v) * tanh_f(pv);
            if (u < 8)
              exch[(mi * 32 + mt * 16 + q * 4 + r) * 8 + u] = u0;
          }
      }
      __syncthreads();
      if (ni == 1) {
        _Float16* h1wr = hbL(1, t & 1);
        #pragma unroll
        for (int mt = 0; mt < 2; ++mt)
          #pragma unroll
          for (int r = 0; r < 4; ++r) {
            const float v  = acc[mt][r];
            const float pv = __shfl_xor(v, 8);
            const int   m  = mi * 32 + mt * 16 + q * 4 + r;
            const float u0 = (u < 8) ? exch[m * 8 + u] : 0.0f;
            const float co = (u < 8) ? cst[512 + m * 8 + u] : 0.0f;
            const float cn = sigm(v) * co + u0;
            const float hh = sigm(pv) * tanh_f(cn);
            if (u < 8) cst[512 + m * 8 + u] = cn;
            const float other = __shfl_xor(hh, 1);
            if (!(u & 1) && u < 8)
              store_h_pair8(h1wr, w, u, m, hh, other);
          }
      }
    }
    group_barrier(ctr, &phase, zz);   // b2: h1(t) visible group-wide

    // ======== FC (redundant per WG, Wfc from LDS) ========
    {
      const _Float16* h1nw = hbL(1, t & 1);
      f32x4 accF[2][2];
      #pragma unroll
      for (int mt = 0; mt < 2; ++mt)
        #pragma unroll
        for (int nt = 0; nt < 2; ++nt) {
          f32x4 v; v[0] = biasFC[nt]; v[1] = biasFC[nt]; v[2] = biasFC[nt]; v[3] = biasFC[nt];
          accF[mt][nt] = v;
        }
      #pragma unroll
      for (int kt = 0; kt < 8; ++kt) {
        half8 a[2], b[2];
        #pragma unroll
        for (int mt = 0; mt < 2; ++mt)
          a[mt] = ld_frag(h1nw, (kt * 4 + q) * 64 + (mi * 32 + mt * 16 + u));
        #pragma unroll
        for (int nt = 0; nt < 2; ++nt)
          b[nt] = *(const half8*)(wfc + (size_t)((kt * 4 + q) * 64 + ni * 32 + nt * 16 + u) * 8);
        #pragma unroll
        for (int mt = 0; mt < 2; ++mt)
          #pragma unroll
          for (int nt = 0; nt < 2; ++nt)
            accF[mt][nt] = __builtin_amdgcn_mfma_f32_16x16x32_f16(a[mt], b[nt], accF[mt][nt], 0, 0, 0);
      }
      #pragma unroll
      for (int mt = 0; mt < 2; ++mt)
        #pragma unroll
        for (int nt = 0; nt < 2; ++nt)
          #pragma unroll
          for (int r = 0; r < 4; ++r)
            predx[(mi * 32 + mt * 16 + q * 4 + r) * 72 + ni * 32 + nt * 16 + u] =
                (_Float16)accF[mt][nt][r];
    }
    __syncthreads();
    // ======== softmax in-place (predx: pred -> out/x), out write ========
    {
      const int row = tid >> 2;   // group-local chain
      const int cg  = tid & 3;    // 16-col group
      _Float16* pr = predx + row * 72 + cg * 16;
      float p[16];
      #pragma unroll
      for (int j = 0; j < 16; ++j) p[j] = (float)pr[j];
      float mx = -3.0e38f;
      #pragma unroll
      for (int j = 0; j < 16; ++j)
        if (!(cg == 3 && j == 15)) mx = fmaxf(mx, p[j]);   // exclude col 63 (dur)
      mx = fmaxf(mx, __shfl_xor(mx, 1));
      mx = fmaxf(mx, __shfl_xor(mx, 2));
      float sm = 0.0f;
      #pragma unroll
      for (int j = 0; j < 16; ++j)
        if (!(cg == 3 && j == 15)) sm += __expf(p[j] - mx);
      sm += __shfl_xor(sm, 1);
      sm += __shfl_xor(sm, 2);
      const float lz = mx + __logf(sm);
      float o[16];
      #pragma unroll
      for (int j = 0; j < 16; ++j) o[j] = p[j] - lz;
      if (cg == 3) o[15] = sigm(p[15]);                    // duration = sigmoid(pred[63])
      #pragma unroll
      for (int j = 0; j < 16; ++j) pr[j] = (_Float16)o[j]; // feedback x (in place)
      if ((row >> 1) == w) {                               // each WG writes 2 of 64 rows
        const int ch = g * 64 + row;
        float* dst = out + ((size_t)ch * TSTEPS + t) * 64 + cg * 16;
        #pragma unroll
        for (int j = 0; j < 16; ++j) dst[j] = o[j];
      }
    }
    __syncthreads();
  }

  // ---------------- final h_f, c_f ----------------
  // h from parity-1 buffers (own chunk, own writes => L1-coherent); c from LDS.
  if (ni == 1 && u < 8) {
    float* hfp = out + OUT_ELEMS;
    float* cfp = out + OUT_ELEMS + HF_ELEMS;
    #pragma unroll
    for (int mt = 0; mt < 2; ++mt)
      #pragma unroll
      for (int r = 0; r < 4; ++r) {
        const int m  = mi * 32 + mt * 16 + q * 4 + r;
        const int ch = g * 64 + m;
        const size_t idx = (size_t)ch * 256 + w * 8 + u;
        hfp[idx]          = (float)hbL(0, 1)[(size_t)(w * 64 + m) * 8 + u];
        hfp[262144 + idx] = (float)hbL(1, 1)[(size_t)(w * 64 + m) * 8 + u];
        cfp[idx]          = cst[m * 8 + u];
        cfp[262144 + idx] = cst[512 + m * 8 + u];
      }
  }
}

extern "C" void kernel_launch(void* const* d_in, const int* in_sizes, int n_in,
                              void* d_out, int out_size, void* d_ws, size_t ws_size,
                              hipStream_t stream) {
  (void)in_sizes; (void)n_in; (void)out_size;
  if (ws_size < (size_t)WS_NEEDED) return;

  const float* h0   = (const float*)d_in[1];
  const float* c0   = (const float*)d_in[2];
  const float* Wih0 = (const float*)d_in[3];
  const float* Whh0 = (const float*)d_in[4];
  const float* bih0 = (const float*)d_in[5];
  const float* bhh0 = (const float*)d_in[6];
  const float* Wih1 = (const float*)d_in[7];
  const float* Whh1 = (const float*)d_in[8];
  const float* bih1 = (const float*)d_in[9];
  const float* bhh1 = (const float*)d_in[10];
  const float* Wfc  = (const float*)d_in[11];
  const float* bfc  = (const float*)d_in[12];
  float* outp = (float*)d_out;
  char*  wsp  = (char*)d_ws;

  // zero barrier + slot counters (ws is re-poisoned to 0xAA before every
  // launch; end-of-dispatch flush of the memset makes zeros globally visible)
  hipMemsetAsync(d_ws, 0, WS_HBUF_OFF, stream);

  void* args[] = { &h0, &c0, &Wih0, &Whh0, &bih0, &bhh0, &Wih1, &Whh1,
                   &bih1, &bhh1, &Wfc, &bfc, &outp, &wsp };
  hipError_t e = hipLaunchCooperativeKernel((const void*)decoder_kernel,
                                            dim3(NGROUP * GWG), dim3(NTHR),
                                            args, 0u, stream);
  if (e != hipSuccess) {
    // fallback: plain launch (512 blocks at 2/CU are co-resident; proven R6)
    decoder_kernel<<<dim3(NGROUP * GWG), dim3(NTHR), 0, stream>>>(
        h0, c0, Wih0, Whh0, bih0, bhh0, Wih1, Whh1, bih1, bhh1, Wfc, bfc, outp, wsp);
  }
}

// Round 7
// 5309.988 us; speedup vs baseline: 1.2918x; 1.2918x over previous
//
#include <hip/hip_runtime.h>
#include <stdint.h>
#include <stddef.h>

// Persistent 2-layer LSTM decoder, B=1024, H=256, T=512.
// 16 groups x 16 WGs x 256 threads (1 block/CU). WG owns 16 hidden units.
//
// R11: SOFTWARE ANTIPHASE. Each group's 64 chains split into two virtual
// batches A/B of 32 (M=32). One wave time-multiplexes both batches with the
// schedule L0_A,arrA | L0_B,arrB | waitA,L1_A,arrA | waitB,L1_B,arrB |
// waitA,FC_A | waitB,FC_B — every barrier WAIT is preceded by a full
// compute phase of the other batch issued after the matching ARRIVE, so
// polls succeed on the first RMW. Antiphase by program order: no occupancy
// cost, weights SHARED between batches (R6/R9 showed 2 blocks/CU can't hold
// them). Evidence base: R7 (split RMW arrive/wait: correct, proven), R5
// (stage+hf data path, 4879us best), R8/R10 (load-based flag polls hang —
// sc0 load does not reliably bypass L1; POLLING MUST BE RMW).
//
// Mechanisms (all proven in passing rounds):
//  - barrier: split-phase RMW arrive/poll at XCD-L2 + buffer_inv sc0
//    acquire (R7); two counters per group (A/B) 128B apart.
//  - h-buffers: single-parity per batch/layer, chunked f16 in L2;
//    write-through stores; race-free by the b1/b2 ordering (R5 argument).
//  - SB0 staging via global_load_lds (16KB per batch) after b1; h1 frags
//    retained in registers across b2 (FC(t) frags == L1(t+1) h1_prev).
//  - XCD-local groups via HW_REG_XCC_ID + slot claim.
//
// h-buffer layout (per group, per layer, per batch): chunked f16
//   f16_index = (c*32 + m)*8 + e, c = unit/8 (0..31), m = chain (0..31),
//   e = unit%8. A-fragment = one 16B chunk; chunk c = contiguous 512B.

#define NGROUP 16
#define GWG    16
#define NTHR   256
#define TSTEPS 512

typedef _Float16 half8 __attribute__((ext_vector_type(8)));
typedef float    f32x4 __attribute__((ext_vector_type(4)));

#define OUT_ELEMS   33554432   // 1024*512*64
#define HF_ELEMS    524288     // 2*1024*256
#define HBUF_ELEMS  8192       // 32*256 f16 per layer per batch (16KB)
#define GROUP_WS_BYTES 65536   // 4 bufs (2 layer x 2 batch) * 16KB
#define WS_SLOT_OFF 4096
#define WS_HBUF_OFF 8192
#define WS_NEEDED   (WS_HBUF_OFF + NGROUP * GROUP_WS_BYTES)

__device__ __forceinline__ float sigm(float x)   { return 1.0f / (1.0f + __expf(-x)); }
__device__ __forceinline__ float tanh_f(float x) { return 1.0f - 2.0f / (__expf(2.0f * x) + 1.0f); }

// 16B A-fragment plain load from a chunked h-buffer in L2.
__device__ __forceinline__ half8 ld_frag(const _Float16* buf, int idx16) {
  return *(const half8*)(buf + (size_t)idx16 * 8);
}

// 16KB linear global->LDS copy (zero VGPR dest). 4 insts/wave.
__device__ __forceinline__ void stage16k(const void* src, void* lds_dst, int tid) {
  const int wv = tid >> 6;
  const int ln = tid & 63;
  const char* s = (const char*)src + ln * 16;
  char* d = (char*)lds_dst;
  #pragma unroll
  for (int i = 0; i < 4; ++i) {
    const int off = (i * 4 + wv) * 1024;
    __builtin_amdgcn_global_load_lds(
        (const __attribute__((address_space(1))) void*)(s + off),
        (__attribute__((address_space(3))) void*)(d + off),
        16, 0, 0);
  }
}

// Packed f16x2 store of (unit u,u+1) for chain m (0..31). Even-u lanes only.
__device__ __forceinline__ void store_h_pair32(_Float16* hw, int w, int u, int m,
                                               float lo, float hi) {
  union { _Float16 h[2]; uint32_t u32; } pk;
  pk.h[0] = (_Float16)lo; pk.h[1] = (_Float16)hi;
  const int c = w * 2 + (u >> 3);
  *((uint32_t*)hw + (size_t)(c * 32 + m) * 4 + ((u & 7) >> 1)) = pk.u32;
}

// Split-phase RMW group barrier (R7-proven). ARRIVE: sync (drains vmcnt =>
// h stores in XCD L2) + tid0 fetch_add. WAIT: tid0 RMW-polls (zz = opaque
// zero defeats the atomicrmw-add-0 -> load fold), buffer_inv sc0 acquire,
// block rendezvous.
#define ARRIVEB(CTR) do { \
  __syncthreads(); \
  if (tid == 0) __hip_atomic_fetch_add((CTR), 1, __ATOMIC_RELEASE, __HIP_MEMORY_SCOPE_WORKGROUP); \
} while (0)

#define WAITB(CTR, PH) do { \
  if (tid == 0) { \
    const int tgt_ = GWG * (++(PH)); \
    while (__hip_atomic_fetch_add((CTR), zz, __ATOMIC_RELAXED, __HIP_MEMORY_SCOPE_WORKGROUP) < tgt_) \
      __builtin_amdgcn_s_sleep(1); \
    asm volatile("buffer_inv sc0" ::: "memory"); \
  } \
  __syncthreads(); \
} while (0)

__global__ __launch_bounds__(NTHR, 1)
void decoder_kernel(const float* __restrict__ h0in, const float* __restrict__ c0in,
                    const float* __restrict__ Wih0, const float* __restrict__ Whh0,
                    const float* __restrict__ bih0, const float* __restrict__ bhh0,
                    const float* __restrict__ Wih1, const float* __restrict__ Whh1,
                    const float* __restrict__ bih1, const float* __restrict__ bhh1,
                    const float* __restrict__ Wfc,  const float* __restrict__ bfc,
                    float* __restrict__ out, char* __restrict__ ws)
{
  const int tid  = threadIdx.x;
  const int lane = tid & 63;
  const int wave = tid >> 6;
  const int mi   = wave >> 1;   // M half: 16 chains of the 32-chain batch
  const int ni   = wave & 1;    // gate pair: 0 -> {i,g}, 1 -> {f,o}
  const int q    = lane >> 4;   // quad
  const int u    = lane & 15;   // unit-in-slice / frag col / frag m

  int zz;
  asm volatile("s_mov_b32 %0, 0" : "=s"(zz));   // opaque zero

  // ---- derive (group g, member w) from the physical XCD id ----
  __shared__ int s_gw[2];
  if (tid == 0) {
    uint32_t xcc;
    asm volatile("s_getreg_b32 %0, hwreg(HW_REG_XCC_ID)" : "=s"(xcc));
    xcc &= 7;
    const int slot = atomicAdd((int*)(ws + WS_SLOT_OFF) + (size_t)xcc * 32, 1);  // device-scope, once
    s_gw[0] = (int)xcc * 2 + (slot >> 4);   // group 0..15 (2 per XCD)
    s_gw[1] = slot & 15;                    // member 0..15 (unit slice)
  }
  __syncthreads();
  const int g = s_gw[0];
  const int w = s_gw[1];

  int* ctrA = (int*)(ws + (size_t)g * 256);
  int* ctrB = ctrA + 32;                     // 128B apart
  _Float16* hbuf = (_Float16*)(ws + WS_HBUF_OFF + (size_t)g * GROUP_WS_BYTES);
  #define H0B(V) (hbuf + (V) * HBUF_ELEMS)
  #define H1B(V) (hbuf + (2 + (V)) * HBUF_ELEMS)

  __shared__ __align__(16) _Float16 sb0[2][HBUF_ELEMS];  // staged h0 per batch (16KB x2)
  __shared__ __align__(16) _Float16 xbuf[2][32 * 72];    // feedback x per batch (72 = bank pad)
  __shared__ __align__(16) float    exch[8 * 64];        // u0 exchange (transient, shared)
  __shared__ __align__(16) float    predbuf[32 * 68];    // FC out (transient, shared)

  // ---------------- weight fragments (register/AGPR-resident, f16) ----------------
  // Shared by both batches. B-frag: n=lane&15, k=q*8+j. Same tiling as R5.
  half8 bL0[2][10]; half8 bL1[2][16]; half8 bFC[2][8];
  float biasL0[2], biasL1[2], biasFC[2];
  #pragma unroll
  for (int nt = 0; nt < 2; ++nt) {
    // ni=0 tiles {i(0), g(512)}, ni=1 tiles {f(256), o(768)}
    const int base0 = (ni == 0) ? (nt == 0 ? 0 : 512) : (nt == 0 ? 256 : 768);
    const int row = base0 + w * 16 + u;
    biasL0[nt] = bih0[row] + bhh0[row];
    biasL1[nt] = bih1[row] + bhh1[row];
    #pragma unroll
    for (int kt = 0; kt < 10; ++kt) {   // L0: K = 64(x) + 256(h0)
      const int k0 = kt * 32 + q * 8;
      const float* src = (kt < 2) ? (Wih0 + (size_t)row * 64 + k0)
                                  : (Whh0 + (size_t)row * 256 + (k0 - 64));
      half8 v;
      #pragma unroll
      for (int j = 0; j < 8; ++j) v[j] = (_Float16)src[j];
      bL0[nt][kt] = v;
    }
    #pragma unroll
    for (int kt = 0; kt < 16; ++kt) {   // L1: K = 256(h0new) + 256(h1)
      const int k0 = kt * 32 + q * 8;
      const float* src = (kt < 8) ? (Wih1 + (size_t)row * 256 + k0)
                                  : (Whh1 + (size_t)row * 256 + (k0 - 256));
      half8 v;
      #pragma unroll
      for (int j = 0; j < 8; ++j) v[j] = (_Float16)src[j];
      bL1[nt][kt] = v;
    }
    const int rowF = ni * 32 + nt * 16 + u;
    biasFC[nt] = bfc[rowF];
    #pragma unroll
    for (int kt = 0; kt < 8; ++kt) {
      const float* src = Wfc + (size_t)rowF * 256 + kt * 32 + q * 8;
      half8 v;
      #pragma unroll
      for (int j = 0; j < 8; ++j) v[j] = (_Float16)src[j];
      bFC[nt][kt] = v;
    }
  }

  // ---------------- state init ----------------
  float c0st[2][4], c1st[2][4], h0sv[2][4], h1sv[2][4];   // [batch][r]
  #pragma unroll
  for (int v = 0; v < 2; ++v)
    #pragma unroll
    for (int r = 0; r < 4; ++r) { c0st[v][r] = 0; c1st[v][r] = 0; h0sv[v][r] = 0; h1sv[v][r] = 0; }
  if (ni == 1) {
    #pragma unroll
    for (int v = 0; v < 2; ++v)
      #pragma unroll
      for (int r = 0; r < 4; ++r) {
        const int ch = g * 64 + v * 32 + mi * 16 + q * 4 + r;
        c0st[v][r] = c0in[(size_t)ch * 256 + w * 16 + u];
        c1st[v][r] = c0in[262144 + (size_t)ch * 256 + w * 16 + u];
      }
  }
  // initial h -> chunked L2 buffers (own chunks c = 2w, 2w+1)
  if (tid < 64) {
    const int m  = tid & 31;
    const int cc = tid >> 5;            // 0..1
    const int c  = w * 2 + cc;
    #pragma unroll
    for (int l = 0; l < 2; ++l)
      #pragma unroll
      for (int v = 0; v < 2; ++v) {
        const float* s = h0in + (size_t)l * 262144 + (size_t)(g * 64 + v * 32 + m) * 256 + c * 8;
        half8 pk;
        #pragma unroll
        for (int j = 0; j < 8; ++j) pk[j] = (_Float16)s[j];
        *(half8*)((l ? H1B(v) : H0B(v)) + (size_t)(c * 32 + m) * 8) = pk;
      }
  }
  for (int i = tid; i < 2 * 32 * 64; i += NTHR) {  // x0: col 61 (= INPUT_SIZE-3) = 1
    const int v = i >> 11, row = (i >> 6) & 31, col = i & 63;
    xbuf[v][row * 72 + col] = (col == 61) ? (_Float16)1.0f : (_Float16)0.0f;
  }

  int phA = 0, phB = 0;
  ARRIVEB(ctrA);
  WAITB(ctrA, phA);

  // Prologue: stage SB0_A/B <- h0(init); hf_A/B <- h1(init) frags (retained).
  half8 hfA[8], hfB[8];
  stage16k(H0B(0), &sb0[0][0], tid);
  stage16k(H0B(1), &sb0[1][0], tid);
  #pragma unroll
  for (int kt = 0; kt < 8; ++kt) {
    hfA[kt] = ld_frag(H1B(0), (kt * 4 + q) * 32 + (mi * 16 + u));
    hfB[kt] = ld_frag(H1B(1), (kt * 4 + q) * 32 + (mi * 16 + u));
  }
  __syncthreads();   // drain staging + hf loads, all waves

  // ---- phase macros (V is a literal: all state indices compile-time) ----
  #define L0_PHASE(V) do { \
    f32x4 a0_, a1_; \
    a0_[0]=biasL0[0]; a0_[1]=biasL0[0]; a0_[2]=biasL0[0]; a0_[3]=biasL0[0]; \
    a1_[0]=biasL0[1]; a1_[1]=biasL0[1]; a1_[2]=biasL0[1]; a1_[3]=biasL0[1]; \
    const int m_ = mi * 16 + u; \
    _Pragma("unroll") \
    for (int kt = 0; kt < 10; ++kt) { \
      half8 af_; \
      if (kt < 2) af_ = *(const half8*)(xbuf[V] + m_ * 72 + kt * 32 + q * 8); \
      else        af_ = *(const half8*)(sb0[V] + (size_t)((kt * 4 - 8 + q) * 32 + m_) * 8); \
      a0_ = __builtin_amdgcn_mfma_f32_16x16x32_f16(af_, bL0[0][kt], a0_, 0, 0, 0); \
      a1_ = __builtin_amdgcn_mfma_f32_16x16x32_f16(af_, bL0[1][kt], a1_, 0, 0, 0); \
    } \
    if (ni == 0) { \
      _Pragma("unroll") \
      for (int r = 0; r < 4; ++r) \
        exch[(mi * 4 + r) * 64 + lane] = sigm(a0_[r]) * tanh_f(a1_[r]); \
    } \
    __syncthreads(); \
    if (ni == 1) { \
      _Pragma("unroll") \
      for (int r = 0; r < 4; ++r) { \
        const float u0_ = exch[(mi * 4 + r) * 64 + lane]; \
        const float cn_ = sigm(a0_[r]) * c0st[V][r] + u0_; \
        c0st[V][r] = cn_; \
        const float hh_ = sigm(a1_[r]) * tanh_f(cn_); \
        h0sv[V][r] = hh_; \
        const float ot_ = __shfl_xor(hh_, 1); \
        if (!(u & 1)) store_h_pair32(H0B(V), w, u, mi * 16 + q * 4 + r, hh_, ot_); \
      } \
    } \
  } while (0)

  #define L1_PHASE(V, HF) do { \
    stage16k(H0B(V), &sb0[V][0], tid); \
    f32x4 a0_, a1_; \
    a0_[0]=biasL1[0]; a0_[1]=biasL1[0]; a0_[2]=biasL1[0]; a0_[3]=biasL1[0]; \
    a1_[0]=biasL1[1]; a1_[1]=biasL1[1]; a1_[2]=biasL1[1]; a1_[3]=biasL1[1]; \
    _Pragma("unroll") \
    for (int kk = 0; kk < 8; ++kk) {          /* h1_prev half: retained regs */ \
      a0_ = __builtin_amdgcn_mfma_f32_16x16x32_f16(HF[kk], bL1[0][kk + 8], a0_, 0, 0, 0); \
      a1_ = __builtin_amdgcn_mfma_f32_16x16x32_f16(HF[kk], bL1[1][kk + 8], a1_, 0, 0, 0); \
    } \
    __syncthreads();                          /* drain SB0 stage (all waves) */ \
    const int m_ = mi * 16 + u; \
    _Pragma("unroll") \
    for (int kt = 0; kt < 8; ++kt) {          /* h0_new half from SB0 */ \
      const half8 af_ = *(const half8*)(sb0[V] + (size_t)((kt * 4 + q) * 32 + m_) * 8); \
      a0_ = __builtin_amdgcn_mfma_f32_16x16x32_f16(af_, bL1[0][kt], a0_, 0, 0, 0); \
      a1_ = __builtin_amdgcn_mfma_f32_16x16x32_f16(af_, bL1[1][kt], a1_, 0, 0, 0); \
    } \
    if (ni == 0) { \
      _Pragma("unroll") \
      for (int r = 0; r < 4; ++r) \
        exch[(mi * 4 + r) * 64 + lane] = sigm(a0_[r]) * tanh_f(a1_[r]); \
    } \
    __syncthreads(); \
    if (ni == 1) { \
      _Pragma("unroll") \
      for (int r = 0; r < 4; ++r) { \
        const float u0_ = exch[(mi * 4 + r) * 64 + lane]; \
        const float cn_ = sigm(a0_[r]) * c1st[V][r] + u0_; \
        c1st[V][r] = cn_; \
        const float hh_ = sigm(a1_[r]) * tanh_f(cn_); \
        h1sv[V][r] = hh_; \
        const float ot_ = __shfl_xor(hh_, 1); \
        if (!(u & 1)) store_h_pair32(H1B(V), w, u, mi * 16 + q * 4 + r, hh_, ot_); \
      } \
    } \
  } while (0)

  #define FC_PHASE(V, HF, T) do { \
    _Pragma("unroll") \
    for (int kt = 0; kt < 8; ++kt)            /* reload h1_new; retained for L1(t+1) */ \
      HF[kt] = ld_frag(H1B(V), (kt * 4 + q) * 32 + (mi * 16 + u)); \
    f32x4 a0_, a1_; \
    a0_[0]=biasFC[0]; a0_[1]=biasFC[0]; a0_[2]=biasFC[0]; a0_[3]=biasFC[0]; \
    a1_[0]=biasFC[1]; a1_[1]=biasFC[1]; a1_[2]=biasFC[1]; a1_[3]=biasFC[1]; \
    _Pragma("unroll") \
    for (int kt = 0; kt < 8; ++kt) { \
      a0_ = __builtin_amdgcn_mfma_f32_16x16x32_f16(HF[kt], bFC[0][kt], a0_, 0, 0, 0); \
      a1_ = __builtin_amdgcn_mfma_f32_16x16x32_f16(HF[kt], bFC[1][kt], a1_, 0, 0, 0); \
    } \
    _Pragma("unroll") \
    for (int r = 0; r < 4; ++r) { \
      predbuf[(mi * 16 + q * 4 + r) * 68 + ni * 32 + u] = a0_[r]; \
      predbuf[(mi * 16 + q * 4 + r) * 68 + ni * 32 + 16 + u] = a1_[r]; \
    } \
    __syncthreads(); \
    { \
      const int row_ = tid >> 3;              /* 0..31 */ \
      const int cg_  = tid & 7;               /* 8 cols each */ \
      const float* pr_ = predbuf + row_ * 68 + cg_ * 8; \
      float p_[8]; \
      _Pragma("unroll") \
      for (int j = 0; j < 8; ++j) p_[j] = pr_[j]; \
      float mx_ = -3.0e38f; \
      _Pragma("unroll") \
      for (int j = 0; j < 8; ++j) \
        if (!(cg_ == 7 && j == 7)) mx_ = fmaxf(mx_, p_[j]); \
      mx_ = fmaxf(mx_, __shfl_xor(mx_, 1)); \
      mx_ = fmaxf(mx_, __shfl_xor(mx_, 2)); \
      mx_ = fmaxf(mx_, __shfl_xor(mx_, 4)); \
      float sm_ = 0.0f; \
      _Pragma("unroll") \
      for (int j = 0; j < 8; ++j) \
        if (!(cg_ == 7 && j == 7)) sm_ += __expf(p_[j] - mx_); \
      sm_ += __shfl_xor(sm_, 1); \
      sm_ += __shfl_xor(sm_, 2); \
      sm_ += __shfl_xor(sm_, 4); \
      const float lz_ = mx_ + __logf(sm_); \
      float o_[8]; \
      _Pragma("unroll") \
      for (int j = 0; j < 8; ++j) o_[j] = p_[j] - lz_; \
      if (cg_ == 7) o_[7] = sigm(p_[7]);      /* duration = sigmoid(pred[63]) */ \
      _Float16* xw_ = xbuf[V] + row_ * 72 + cg_ * 8; \
      _Pragma("unroll") \
      for (int j = 0; j < 8; ++j) xw_[j] = (_Float16)o_[j]; \
      if ((row_ >> 1) == w) {                 /* 2 of 32 rows per WG */ \
        const int ch_ = g * 64 + (V) * 32 + row_; \
        float* dst_ = out + ((size_t)ch_ * TSTEPS + (T)) * 64 + cg_ * 8; \
        _Pragma("unroll") \
        for (int j = 0; j < 8; ++j) dst_[j] = o_[j]; \
      } \
    } \
    __syncthreads(); \
  } while (0)

  // ---------------- time loop: antiphase A/B schedule ----------------
  for (int t = 0; t < TSTEPS; ++t) {
    L0_PHASE(0);  ARRIVEB(ctrA);        // b1_A
    L0_PHASE(1);  ARRIVEB(ctrB);        // b1_B  (covers waitA below)
    WAITB(ctrA, phA);
    L1_PHASE(0, hfA);  ARRIVEB(ctrA);   // b2_A  (L1_A covers waitB below)
    WAITB(ctrB, phB);
    L1_PHASE(1, hfB);  ARRIVEB(ctrB);   // b2_B  (L1_B covers waitA below)
    WAITB(ctrA, phA);
    FC_PHASE(0, hfA, t);                // FC_A+softmax covers waitB below
    WAITB(ctrB, phB);
    FC_PHASE(1, hfB, t);
  }

  // ---------------- final h_f, c_f ----------------
  if (ni == 1) {
    float* hfp = out + OUT_ELEMS;
    float* cfp = out + OUT_ELEMS + HF_ELEMS;
    #pragma unroll
    for (int v = 0; v < 2; ++v)
      #pragma unroll
      for (int r = 0; r < 4; ++r) {
        const int ch = g * 64 + v * 32 + mi * 16 + q * 4 + r;
        const size_t idx = (size_t)ch * 256 + w * 16 + u;
        hfp[idx]          = h0sv[v][r];
        hfp[262144 + idx] = h1sv[v][r];
        cfp[idx]          = c0st[v][r];
        cfp[262144 + idx] = c1st[v][r];
      }
  }
}

extern "C" void kernel_launch(void* const* d_in, const int* in_sizes, int n_in,
                              void* d_out, int out_size, void* d_ws, size_t ws_size,
                              hipStream_t stream) {
  (void)in_sizes; (void)n_in; (void)out_size;
  if (ws_size < (size_t)WS_NEEDED) return;

  const float* h0   = (const float*)d_in[1];
  const float* c0   = (const float*)d_in[2];
  const float* Wih0 = (const float*)d_in[3];
  const float* Whh0 = (const float*)d_in[4];
  const float* bih0 = (const float*)d_in[5];
  const float* bhh0 = (const float*)d_in[6];
  const float* Wih1 = (const float*)d_in[7];
  const float* Whh1 = (const float*)d_in[8];
  const float* bih1 = (const float*)d_in[9];
  const float* bhh1 = (const float*)d_in[10];
  const float* Wfc  = (const float*)d_in[11];
  const float* bfc  = (const float*)d_in[12];
  float* outp = (float*)d_out;
  char*  wsp  = (char*)d_ws;

  // zero barrier counters + slot counters (ws re-poisoned to 0xAA pre-launch)
  hipMemsetAsync(d_ws, 0, WS_HBUF_OFF, stream);

  void* args[] = { &h0, &c0, &Wih0, &Whh0, &bih0, &bhh0, &Wih1, &Whh1,
                   &bih1, &bhh1, &Wfc, &bfc, &outp, &wsp };
  hipError_t e = hipLaunchCooperativeKernel((const void*)decoder_kernel,
                                            dim3(NGROUP * GWG), dim3(NTHR),
                                            args, 0u, stream);
  if (e != hipSuccess) {
    // fallback: plain launch (256 full-CU blocks on 256 CUs are co-resident)
    decoder_kernel<<<dim3(NGROUP * GWG), dim3(NTHR), 0, stream>>>(
        h0, c0, Wih0, Whh0, bih0, bhh0, Wih1, Whh1, bih1, bhh1, Wfc, bfc, outp, wsp);
  }
}

// Round 8
// 3340.416 us; speedup vs baseline: 2.0535x; 1.5896x over previous
//
#include <hip/hip_runtime.h>
#include <stdint.h>
#include <stddef.h>

// Persistent 2-layer LSTM decoder, B=1024, H=256, T=512.
//
// R12: 2 waves/SIMD of the SAME group via one 512-thread block per CU.
// Evidence chain: R7 (fill arrive->wait windows) null, R11 (guaranteed
// pre-satisfied waits) null => the ~16k cyc/step idle is NOT barrier
// waiting; it is per-wave exposed dependent latency (MFMA acc chains,
// quarter-rate transcendental chains concentrated on 2 of 4 waves, LDS/L2
// read latency) at 1 wave/SIMD. Latency stalls are covered by ANY
// co-resident wave — same-group is fine. R6/R9 failed co-residency because
// 2 blocks duplicated 272 weight VGPRs; here 8 waves share one block:
//  - wave (mi, nj): nj owns ONE gate tile (i/f/g/o = nj*256 base), mi owns
//    a 32-chain half. Weights/wave: bL0[10]+bL1[16] = 104 VGPR. Fits
//    256-VGPR @ 2 waves/SIMD with no spill headroom issues.
//  - elementwise gate phase spread over ALL 512 threads (2 units/thread,
//    8x shorter transcendental chains than R5's ni=1-wave concentration);
//    gates exchanged via padded LDS (exch[gate][chain][17]).
//  - h1 staged to LDS sb1 (stage32k after b2) replacing R5's hf register
//    retention (saves 64 VGPR); FC reads h1 from L2 directly (race-free:
//    all h1b writes of t+1 are after b1(t+1) > all FC(t) reads).
//  - Wfc in LDS, chunk-padded (65 frags/c-block) to kill R9's 8-way
//    bank conflict. c-state in registers (elementwise ownership is static).
//  - barrier: R4-R7-proven RMW arrive/poll + buffer_inv sc0 acquire.
// LDS: sb0 32K + sb1 32K + wfc 32.5K + xbuf 9K + exch 17K + predbuf 17K
// = 139.5KB (<160KB, 1 block/CU). Grid 256 x 512.
//
// h-buffer layout (per group, per layer): chunked f16
//   f16_index = (c*64 + m)*8 + e, c = unit/8 (0..31), m = chain (0..63),
//   e = unit%8. A-fragment = one 16B chunk; chunk c = contiguous 1KB
//   (=> linear global_load_lds).

#define NGROUP 16
#define GWG    16
#define NTHR   512
#define TSTEPS 512

typedef _Float16 half8 __attribute__((ext_vector_type(8)));
typedef float    f32x4 __attribute__((ext_vector_type(4)));

#define OUT_ELEMS   33554432   // 1024*512*64
#define HF_ELEMS    524288     // 2*1024*256
#define HBUF_ELEMS  16384      // 64*256 (f16) per layer
#define GROUP_WS_BYTES 65536   // 2 layers * 32KB
#define WS_HBUF_OFF 4096
#define WS_NEEDED   (WS_HBUF_OFF + NGROUP * GROUP_WS_BYTES)

__device__ __forceinline__ float sigm(float x)   { return 1.0f / (1.0f + __expf(-x)); }
__device__ __forceinline__ float tanh_f(float x) { return 1.0f - 2.0f / (__expf(2.0f * x) + 1.0f); }

// XCD-local group barrier (R4-R7 proven RMW mechanism). Entry __syncthreads
// drains vmcnt (write-through L1 => prior h stores in XCD L2). Arrive/poll
// are real RMWs at the L2 (zz = opaque zero defeats the atomicrmw-add-0 ->
// load fold). Acquire = L1-only invalidate, then block rendezvous.
__device__ __forceinline__ void group_barrier(int* ctr, int* phase, int zz) {
  __syncthreads();
  if (threadIdx.x == 0) {
    __hip_atomic_fetch_add(ctr, 1, __ATOMIC_RELEASE, __HIP_MEMORY_SCOPE_WORKGROUP);
    const int target = GWG * (++(*phase));
    while (__hip_atomic_fetch_add(ctr, zz, __ATOMIC_RELAXED, __HIP_MEMORY_SCOPE_WORKGROUP) < target)
      __builtin_amdgcn_s_sleep(1);
    asm volatile("buffer_inv sc0" ::: "memory");   // L1-only invalidate (gfx940+)
  }
  __syncthreads();
}

// 16B A-fragment plain load from a chunked h-buffer in L2.
__device__ __forceinline__ half8 ld_frag(const _Float16* buf, int idx16) {
  return *(const half8*)(buf + (size_t)idx16 * 8);
}

// 32KB linear global->LDS copy, zero VGPR destination, 8-wave version:
// 4 insts/wave, wave wv handles 1KB blocks {i*8+wv}. LDS dest is the
// wave-uniform base + lane*16 (m97/m104 semantics).
__device__ __forceinline__ void stage32k8(const void* src, void* lds_dst, int tid) {
  const int wv = tid >> 6;
  const int ln = tid & 63;
  const char* s = (const char*)src + ln * 16;
  char* d = (char*)lds_dst;
  #pragma unroll
  for (int i = 0; i < 4; ++i) {
    const int off = (i * 8 + wv) * 1024;
    __builtin_amdgcn_global_load_lds(
        (const __attribute__((address_space(1))) void*)(s + off),
        (__attribute__((address_space(3))) void*)(d + off),
        16, 0, 0);
  }
}

__global__ __launch_bounds__(NTHR, 2)
void decoder_kernel(const float* __restrict__ h0in, const float* __restrict__ c0in,
                    const float* __restrict__ Wih0, const float* __restrict__ Whh0,
                    const float* __restrict__ bih0, const float* __restrict__ bhh0,
                    const float* __restrict__ Wih1, const float* __restrict__ Whh1,
                    const float* __restrict__ bih1, const float* __restrict__ bhh1,
                    const float* __restrict__ Wfc,  const float* __restrict__ bfc,
                    float* __restrict__ out, char* __restrict__ ws)
{
  const int tid  = threadIdx.x;
  const int lane = tid & 63;
  const int wave = tid >> 6;    // 0..7
  const int mi   = wave >> 2;   // chain half (32 chains)
  const int nj   = wave & 3;    // gate tile: 0=i,1=f,2=g,3=o (base nj*256)
  const int q    = lane >> 4;   // quad
  const int u    = lane & 15;   // frag row/col within 16-tile
  const int em   = tid >> 3;    // elementwise chain (0..63)
  const int eu2  = (tid & 7) * 2;  // elementwise unit pair (0,2,..,14)

  // Opaque zero: an SGPR the compiler cannot constant-fold.
  int zz;
  asm volatile("s_mov_b32 %0, 0" : "=s"(zz));

  // ---- derive (group g, member w) from the physical XCD id ----
  __shared__ int s_gw[2];
  if (tid == 0) {
    uint32_t xcc;
    asm volatile("s_getreg_b32 %0, hwreg(HW_REG_XCC_ID)" : "=s"(xcc));
    xcc &= 7;
    const int slot = atomicAdd((int*)(ws + 2048) + (size_t)xcc * 32, 1);  // device-scope, once
    s_gw[0] = (int)xcc * 2 + (slot >> 4);   // group 0..15 (2 per XCD)
    s_gw[1] = slot & 15;                    // member 0..15 (unit slice)
  }
  __syncthreads();
  const int g = s_gw[0];
  const int w = s_gw[1];

  int* ctr = (int*)(ws + (size_t)g * 128);
  _Float16* h0b = (_Float16*)(ws + WS_HBUF_OFF + (size_t)g * GROUP_WS_BYTES);
  _Float16* h1b = h0b + HBUF_ELEMS;

  __shared__ __align__(16) _Float16 sb0[HBUF_ELEMS];    // staged h0 (32KB)
  __shared__ __align__(16) _Float16 sb1[HBUF_ELEMS];    // staged h1 (32KB)
  __shared__ __align__(16) _Float16 wfcs[32 * 65 * 8];  // Wfc chunked, padded (32.5KB)
  __shared__ __align__(16) _Float16 xbuf[64 * 72];      // feedback x (9KB, bank pad)
  __shared__ __align__(16) float    exch[4 * 64 * 17];  // gates (17KB, stride-17 pad)
  __shared__ __align__(16) float    predbuf[64 * 68];   // FC out (17KB)

  // ---------------- weight fragments (register-resident, f16) ----------------
  // gates = act @ W^T. B-frag: n(row)=u, k=q*8+j. One gate tile per wave.
  half8 bL0[10]; half8 bL1[16];
  float biasL0, biasL1, biasFC;
  {
    const int row = nj * 256 + w * 16 + u;   // torch gate order i,f,g,o
    biasL0 = bih0[row] + bhh0[row];
    biasL1 = bih1[row] + bhh1[row];
    #pragma unroll
    for (int kt = 0; kt < 10; ++kt) {   // L0: K = 64(x) + 256(h0)
      const int k0 = kt * 32 + q * 8;
      const float* src = (kt < 2) ? (Wih0 + (size_t)row * 64 + k0)
                                  : (Whh0 + (size_t)row * 256 + (k0 - 64));
      half8 v;
      #pragma unroll
      for (int j = 0; j < 8; ++j) v[j] = (_Float16)src[j];
      bL0[kt] = v;
    }
    #pragma unroll
    for (int kt = 0; kt < 16; ++kt) {   // L1: K = 256(h0new) + 256(h1)
      const int k0 = kt * 32 + q * 8;
      const float* src = (kt < 8) ? (Wih1 + (size_t)row * 256 + k0)
                                  : (Whh1 + (size_t)row * 256 + (k0 - 256));
      half8 v;
      #pragma unroll
      for (int j = 0; j < 8; ++j) v[j] = (_Float16)src[j];
      bL1[kt] = v;
    }
    biasFC = bfc[nj * 16 + u];          // FC row for this wave's tile
  }
  // Wfc -> LDS, chunk-padded: frag (c,rowF) at (c*65 + rowF)*8, c = k/8.
  for (int i = tid; i < 2048; i += NTHR) {
    const int rowF = i & 63;
    const int c    = i >> 6;
    const float* s = Wfc + (size_t)rowF * 256 + c * 8;
    half8 v;
    #pragma unroll
    for (int j = 0; j < 8; ++j) v[j] = (_Float16)s[j];
    *(half8*)(wfcs + (size_t)(c * 65 + rowF) * 8) = v;
  }

  // ---------------- state init (elementwise ownership: em, units eu2..eu2+1) ----
  float c0st[2], c1st[2], h0sv[2], h1sv[2];
  #pragma unroll
  for (int e = 0; e < 2; ++e) {
    const size_t idx = (size_t)(g * 64 + em) * 256 + w * 16 + eu2 + e;
    c0st[e] = c0in[idx];
    c1st[e] = c0in[262144 + idx];
    h0sv[e] = 0.0f; h1sv[e] = 0.0f;
  }
  {  // initial h -> chunked L2 buffers (own u32 slot per thread per layer)
    const int cg2 = w * 2 + (eu2 >> 3);               // chunk
    const uint32_t slot = (uint32_t)(cg2 * 64 + em) * 4 + ((eu2 & 7) >> 1);
    #pragma unroll
    for (int l = 0; l < 2; ++l) {
      const float* s = h0in + (size_t)l * 262144 + (size_t)(g * 64 + em) * 256 + w * 16 + eu2;
      union { _Float16 h[2]; uint32_t u32; } pk;
      pk.h[0] = (_Float16)s[0]; pk.h[1] = (_Float16)s[1];
      ((uint32_t*)(l ? h1b : h0b))[slot] = pk.u32;
    }
  }
  for (int i = tid; i < 64 * 64; i += NTHR) {  // x0 = zeros, col 61 (= INPUT_SIZE-3) = 1
    const int row = i >> 6, col = i & 63;
    xbuf[row * 72 + col] = (col == 61) ? (_Float16)1.0f : (_Float16)0.0f;
  }

  int phase = 0;
  group_barrier(ctr, &phase, zz);      // initial h visible group-wide

  stage32k8(h0b, sb0, tid);            // sb0 <- h0(init)
  stage32k8(h1b, sb1, tid);            // sb1 <- h1(init)
  __syncthreads();                     // drain staging

  // ---------------- time loop ----------------
  for (int t = 0; t < TSTEPS; ++t) {
    // ======== Layer 0: gates = [x | h0_prev] @ W^T (xbuf + sb0, all LDS) ========
    {
      f32x4 acc[2];
      #pragma unroll
      for (int mt = 0; mt < 2; ++mt) {
        f32x4 v; v[0] = biasL0; v[1] = biasL0; v[2] = biasL0; v[3] = biasL0;
        acc[mt] = v;
      }
      #pragma unroll
      for (int kt = 0; kt < 10; ++kt) {
        half8 a[2];
        #pragma unroll
        for (int mt = 0; mt < 2; ++mt) {
          const int m = mi * 32 + mt * 16 + u;
          if (kt < 2) a[mt] = *(const half8*)(xbuf + m * 72 + kt * 32 + q * 8);
          else        a[mt] = *(const half8*)(sb0 + (size_t)((kt * 4 - 8 + q) * 64 + m) * 8);
        }
        #pragma unroll
        for (int mt = 0; mt < 2; ++mt)
          acc[mt] = __builtin_amdgcn_mfma_f32_16x16x32_f16(a[mt], bL0[kt], acc[mt], 0, 0, 0);
      }
      // scatter gate tile to exch[gate][chain][17]
      #pragma unroll
      for (int mt = 0; mt < 2; ++mt)
        #pragma unroll
        for (int r = 0; r < 4; ++r)
          exch[(nj * 64 + mi * 32 + mt * 16 + q * 4 + r) * 17 + u] = acc[mt][r];
    }
    __syncthreads();
    {  // elementwise L0 (all 512 threads, 2 units each)
      float hv[2];
      #pragma unroll
      for (int e = 0; e < 2; ++e) {
        const int ec = eu2 + e;
        const float iv = exch[(0 * 64 + em) * 17 + ec];
        const float fv = exch[(1 * 64 + em) * 17 + ec];
        const float gv = exch[(2 * 64 + em) * 17 + ec];
        const float ov = exch[(3 * 64 + em) * 17 + ec];
        const float cn = sigm(fv) * c0st[e] + sigm(iv) * tanh_f(gv);
        c0st[e] = cn;
        const float hh = sigm(ov) * tanh_f(cn);
        h0sv[e] = hh; hv[e] = hh;
      }
      union { _Float16 h[2]; uint32_t u32; } pk;
      pk.h[0] = (_Float16)hv[0]; pk.h[1] = (_Float16)hv[1];
      ((uint32_t*)h0b)[(uint32_t)((w * 2 + (eu2 >> 3)) * 64 + em) * 4 + ((eu2 & 7) >> 1)] = pk.u32;
    }
    group_barrier(ctr, &phase, zz);    // b1: h0(t) visible group-wide

    stage32k8(h0b, sb0, tid);          // sb0 <- h0(t); overlaps sb1-half below

    // ======== Layer 1: gates = [h0_new | h1_prev] @ W^T ========
    {
      f32x4 acc[2];
      #pragma unroll
      for (int mt = 0; mt < 2; ++mt) {
        f32x4 v; v[0] = biasL1; v[1] = biasL1; v[2] = biasL1; v[3] = biasL1;
        acc[mt] = v;
      }
      // h1_prev half from sb1 (staged after b2(t-1); drained long ago)
      #pragma unroll
      for (int kt = 8; kt < 16; ++kt) {
        half8 a[2];
        #pragma unroll
        for (int mt = 0; mt < 2; ++mt) {
          const int m = mi * 32 + mt * 16 + u;
          a[mt] = *(const half8*)(sb1 + (size_t)(((kt - 8) * 4 + q) * 64 + m) * 8);
        }
        #pragma unroll
        for (int mt = 0; mt < 2; ++mt)
          acc[mt] = __builtin_amdgcn_mfma_f32_16x16x32_f16(a[mt], bL1[kt], acc[mt], 0, 0, 0);
      }
      __syncthreads();   // drain sb0 staging (all waves)
      // h0_new half from sb0
      #pragma unroll
      for (int kt = 0; kt < 8; ++kt) {
        half8 a[2];
        #pragma unroll
        for (int mt = 0; mt < 2; ++mt) {
          const int m = mi * 32 + mt * 16 + u;
          a[mt] = *(const half8*)(sb0 + (size_t)((kt * 4 + q) * 64 + m) * 8);
        }
        #pragma unroll
        for (int mt = 0; mt < 2; ++mt)
          acc[mt] = __builtin_amdgcn_mfma_f32_16x16x32_f16(a[mt], bL1[kt], acc[mt], 0, 0, 0);
      }
      #pragma unroll
      for (int mt = 0; mt < 2; ++mt)
        #pragma unroll
        for (int r = 0; r < 4; ++r)
          exch[(nj * 64 + mi * 32 + mt * 16 + q * 4 + r) * 17 + u] = acc[mt][r];
    }
    __syncthreads();
    {  // elementwise L1
      float hv[2];
      #pragma unroll
      for (int e = 0; e < 2; ++e) {
        const int ec = eu2 + e;
        const float iv = exch[(0 * 64 + em) * 17 + ec];
        const float fv = exch[(1 * 64 + em) * 17 + ec];
        const float gv = exch[(2 * 64 + em) * 17 + ec];
        const float ov = exch[(3 * 64 + em) * 17 + ec];
        const float cn = sigm(fv) * c1st[e] + sigm(iv) * tanh_f(gv);
        c1st[e] = cn;
        const float hh = sigm(ov) * tanh_f(cn);
        h1sv[e] = hh; hv[e] = hh;
      }
      union { _Float16 h[2]; uint32_t u32; } pk;
      pk.h[0] = (_Float16)hv[0]; pk.h[1] = (_Float16)hv[1];
      ((uint32_t*)h1b)[(uint32_t)((w * 2 + (eu2 >> 3)) * 64 + em) * 4 + ((eu2 & 7) >> 1)] = pk.u32;
    }
    group_barrier(ctr, &phase, zz);    // b2: h1(t) visible group-wide

    stage32k8(h1b, sb1, tid);          // sb1 <- h1(t); drains before L1(t+1) reads

    // ======== FC (redundant per WG): A from h1b (L2), B from wfcs ========
    {
      f32x4 accF[2];
      #pragma unroll
      for (int mt = 0; mt < 2; ++mt) {
        f32x4 v; v[0] = biasFC; v[1] = biasFC; v[2] = biasFC; v[3] = biasFC;
        accF[mt] = v;
      }
      #pragma unroll
      for (int kt = 0; kt < 8; ++kt) {
        const half8 b = *(const half8*)(wfcs + (size_t)((kt * 4 + q) * 65 + nj * 16 + u) * 8);
        half8 a[2];
        #pragma unroll
        for (int mt = 0; mt < 2; ++mt)
          a[mt] = ld_frag(h1b, (kt * 4 + q) * 64 + (mi * 32 + mt * 16 + u));
        #pragma unroll
        for (int mt = 0; mt < 2; ++mt)
          accF[mt] = __builtin_amdgcn_mfma_f32_16x16x32_f16(a[mt], b, accF[mt], 0, 0, 0);
      }
      #pragma unroll
      for (int mt = 0; mt < 2; ++mt)
        #pragma unroll
        for (int r = 0; r < 4; ++r)
          predbuf[(mi * 32 + mt * 16 + q * 4 + r) * 68 + nj * 16 + u] = accF[mt][r];
    }
    __syncthreads();
    {  // softmax + out + feedback (512 threads: 8 cols each)
      const int row = tid >> 3;   // group-local chain
      const int cg  = tid & 7;    // 8-col group
      const float* pr = predbuf + row * 68 + cg * 8;
      float p[8];
      #pragma unroll
      for (int j = 0; j < 8; ++j) p[j] = pr[j];
      float mx = -3.0e38f;
      #pragma unroll
      for (int j = 0; j < 8; ++j)
        if (!(cg == 7 && j == 7)) mx = fmaxf(mx, p[j]);   // exclude col 63 (dur)
      mx = fmaxf(mx, __shfl_xor(mx, 1));
      mx = fmaxf(mx, __shfl_xor(mx, 2));
      mx = fmaxf(mx, __shfl_xor(mx, 4));
      float sm = 0.0f;
      #pragma unroll
      for (int j = 0; j < 8; ++j)
        if (!(cg == 7 && j == 7)) sm += __expf(p[j] - mx);
      sm += __shfl_xor(sm, 1);
      sm += __shfl_xor(sm, 2);
      sm += __shfl_xor(sm, 4);
      const float lz = mx + __logf(sm);
      float o[8];
      #pragma unroll
      for (int j = 0; j < 8; ++j) o[j] = p[j] - lz;
      if (cg == 7) o[7] = sigm(p[7]);                      // duration = sigmoid(pred[63])
      _Float16* xw = xbuf + row * 72 + cg * 8;             // feedback x = out (f16)
      #pragma unroll
      for (int j = 0; j < 8; ++j) xw[j] = (_Float16)o[j];
      if ((row >> 2) == w) {                               // each WG writes 4 of 64 rows
        const int ch = g * 64 + row;
        float* dst = out + ((size_t)ch * TSTEPS + t) * 64 + cg * 8;
        #pragma unroll
        for (int j = 0; j < 8; ++j) dst[j] = o[j];
      }
    }
    __syncthreads();
  }

  // ---------------- final h_f, c_f (elementwise ownership) ----------------
  {
    float* hfp = out + OUT_ELEMS;
    float* cfp = out + OUT_ELEMS + HF_ELEMS;
    #pragma unroll
    for (int e = 0; e < 2; ++e) {
      const size_t idx = (size_t)(g * 64 + em) * 256 + w * 16 + eu2 + e;
      hfp[idx]          = h0sv[e];
      hfp[262144 + idx] = h1sv[e];
      cfp[idx]          = c0st[e];
      cfp[262144 + idx] = c1st[e];
    }
  }
}

extern "C" void kernel_launch(void* const* d_in, const int* in_sizes, int n_in,
                              void* d_out, int out_size, void* d_ws, size_t ws_size,
                              hipStream_t stream) {
  (void)in_sizes; (void)n_in; (void)out_size;
  if (ws_size < (size_t)WS_NEEDED) return;

  const float* h0   = (const float*)d_in[1];
  const float* c0   = (const float*)d_in[2];
  const float* Wih0 = (const float*)d_in[3];
  const float* Whh0 = (const float*)d_in[4];
  const float* bih0 = (const float*)d_in[5];
  const float* bhh0 = (const float*)d_in[6];
  const float* Wih1 = (const float*)d_in[7];
  const float* Whh1 = (const float*)d_in[8];
  const float* bih1 = (const float*)d_in[9];
  const float* bhh1 = (const float*)d_in[10];
  const float* Wfc  = (const float*)d_in[11];
  const float* bfc  = (const float*)d_in[12];
  float* outp = (float*)d_out;
  char*  wsp  = (char*)d_ws;

  // zero barrier + slot counters (ws is re-poisoned to 0xAA before every
  // launch; end-of-dispatch flush of the memset makes zeros globally visible)
  hipMemsetAsync(d_ws, 0, WS_HBUF_OFF, stream);

  void* args[] = { &h0, &c0, &Wih0, &Whh0, &bih0, &bhh0, &Wih1, &Whh1,
                   &bih1, &bhh1, &Wfc, &bfc, &outp, &wsp };
  hipError_t e = hipLaunchCooperativeKernel((const void*)decoder_kernel,
                                            dim3(NGROUP * GWG), dim3(NTHR),
                                            args, 0u, stream);
  if (e != hipSuccess) {
    // fallback: plain launch (256 blocks x 512 thr, 1/CU, co-resident)
    decoder_kernel<<<dim3(NGROUP * GWG), dim3(NTHR), 0, stream>>>(
        h0, c0, Wih0, Whh0, bih0, bhh0, Wih1, Whh1, bih1, bhh1, Wfc, bfc, outp, wsp);
  }
}